// Round 1
// baseline (2898.734 us; speedup 1.0000x reference)
//
#include <hip/hip_runtime.h>

typedef __bf16 bf16x8 __attribute__((ext_vector_type(8)));
typedef __bf16 bf16x2 __attribute__((ext_vector_type(2)));
typedef float  f32x4  __attribute__((ext_vector_type(4)));

#define Bn  512
#define TM1 63
#define DHH 512
#define EHH 512

__device__ __forceinline__ float fast_rcp(float x){ return __builtin_amdgcn_rcpf(x); }
__device__ __forceinline__ float fast_tanh(float x){
    float e = __expf(2.0f*x);
    return 1.0f - 2.0f*fast_rcp(e + 1.0f);
}
__device__ __forceinline__ float fast_sigmoid(float x){
    return fast_rcp(1.0f + __expf(-x));
}

// ---------------- setup kernels ----------------

// Split attn_W1 into dc-part [512n x 1024k] and X-part [512n x 512k]; convert W_hh [2048 x 512].
__global__ __launch_bounds__(256) void k_prep_weights(
    const float* __restrict__ W1, const float* __restrict__ Whh_f,
    __bf16* __restrict__ Wdc, __bf16* __restrict__ W1x, __bf16* __restrict__ Whh)
{
    int i = blockIdx.x*256 + threadIdx.x;
    int n = gridDim.x*256;
    for (int idx = i; idx < 512*1024; idx += n) {
        int f = idx >> 10, k = idx & 1023;
        Wdc[idx] = (__bf16)W1[f*1536 + k];
    }
    for (int idx = i; idx < 512*512; idx += n) {
        int f = idx >> 9, k = idx & 511;
        W1x[idx] = (__bf16)W1[f*1536 + 1024 + k];
    }
    for (int idx = i; idx < 2048*512; idx += n) {
        Whh[idx] = (__bf16)Whh_f[idx];
    }
}

__global__ __launch_bounds__(256) void k_conv_x(const float* __restrict__ X, __bf16* __restrict__ Xb, int n)
{
    int idx = (blockIdx.x*256 + threadIdx.x)*4;
    if (idx < n) {
        float4 v = *(const float4*)(X + idx);
        Xb[idx+0] = (__bf16)v.x; Xb[idx+1] = (__bf16)v.y;
        Xb[idx+2] = (__bf16)v.z; Xb[idx+3] = (__bf16)v.w;
    }
}

// XW[m,f] = sum_e Xbf[m,e]*W1x[f,e] + b1[f], M=32256, N=512, K=512, out bf16
__global__ __launch_bounds__(256) void k_gemm_xw(
    const __bf16* __restrict__ A, const __bf16* __restrict__ Bm,
    const float* __restrict__ bias, __bf16* __restrict__ C)
{
    int tm = blockIdx.x >> 3, tn = blockIdx.x & 7;
    int lane = threadIdx.x & 63, wave = threadIdx.x >> 6;
    int wr = wave >> 1, wc = wave & 1;
    int l15 = lane & 15, l4 = lane >> 4;
    int row_a = tm*64 + wr*32;
    int col_b = tn*64 + wc*32;
    f32x4 acc[2][2] = {};
    const __bf16* Ap = A + (size_t)(row_a + l15)*512 + l4*8;
    const __bf16* Bp = Bm + (size_t)(col_b + l15)*512 + l4*8;
    #pragma unroll 4
    for (int kc = 0; kc < 512; kc += 32) {
        bf16x8 a0 = *(const bf16x8*)(Ap + kc);
        bf16x8 a1 = *(const bf16x8*)(Ap + 16*512 + kc);
        bf16x8 b0 = *(const bf16x8*)(Bp + kc);
        bf16x8 b1 = *(const bf16x8*)(Bp + 16*512 + kc);
        acc[0][0] = __builtin_amdgcn_mfma_f32_16x16x32_bf16(a0,b0,acc[0][0],0,0,0);
        acc[0][1] = __builtin_amdgcn_mfma_f32_16x16x32_bf16(a0,b1,acc[0][1],0,0,0);
        acc[1][0] = __builtin_amdgcn_mfma_f32_16x16x32_bf16(a1,b0,acc[1][0],0,0,0);
        acc[1][1] = __builtin_amdgcn_mfma_f32_16x16x32_bf16(a1,b1,acc[1][1],0,0,0);
    }
    #pragma unroll
    for (int mi=0; mi<2; mi++)
    #pragma unroll
    for (int ni=0; ni<2; ni++) {
        int r0 = row_a + mi*16 + l4*4;
        int c0 = col_b + ni*16 + l15;
        float bv = bias[c0];
        #pragma unroll
        for (int r=0; r<4; r++)
            C[(size_t)(r0+r)*512 + c0] = (__bf16)(acc[mi][ni][r] + bv);
    }
}

// ---------------- per-step kernels ----------------

// blocks 0..63:   dcW [512 x 512]  = dc[512 x 1024k] @ Wdc[512n x 1024k]^T
// blocks 64..319: dWhh [512 x 2048] = d [512 x 512k]  @ Whh[2048n x 512k]^T
__global__ __launch_bounds__(256) void k_step_gemm(
    const __bf16* __restrict__ dc, const __bf16* __restrict__ Wdc,
    const __bf16* __restrict__ Whh, float* __restrict__ dcW, float* __restrict__ dWhh)
{
    int blk = blockIdx.x;
    const __bf16* Bm; float* C; int K, ldb, ldc, tm, tn;
    if (blk < 64) { tm = blk >> 3; tn = blk & 7;  Bm = Wdc; C = dcW;  K = 1024; ldb = 1024; ldc = 512; }
    else { int b2 = blk - 64; tm = b2 >> 5; tn = b2 & 31; Bm = Whh; C = dWhh; K = 512; ldb = 512; ldc = 2048; }

    int lane = threadIdx.x & 63, wave = threadIdx.x >> 6;
    int wr = wave >> 1, wc = wave & 1;
    int l15 = lane & 15, l4 = lane >> 4;
    int row_a = tm*64 + wr*32;
    int col_b = tn*64 + wc*32;
    f32x4 acc[2][2] = {};
    const __bf16* Ap = dc + (size_t)(row_a + l15)*1024 + l4*8;
    const __bf16* Bp = Bm + (size_t)(col_b + l15)*ldb + l4*8;
    #pragma unroll 4
    for (int kc = 0; kc < K; kc += 32) {
        bf16x8 a0 = *(const bf16x8*)(Ap + kc);
        bf16x8 a1 = *(const bf16x8*)(Ap + 16*1024 + kc);
        bf16x8 b0 = *(const bf16x8*)(Bp + kc);
        bf16x8 b1 = *(const bf16x8*)(Bp + (size_t)16*ldb + kc);
        acc[0][0] = __builtin_amdgcn_mfma_f32_16x16x32_bf16(a0,b0,acc[0][0],0,0,0);
        acc[0][1] = __builtin_amdgcn_mfma_f32_16x16x32_bf16(a0,b1,acc[0][1],0,0,0);
        acc[1][0] = __builtin_amdgcn_mfma_f32_16x16x32_bf16(a1,b0,acc[1][0],0,0,0);
        acc[1][1] = __builtin_amdgcn_mfma_f32_16x16x32_bf16(a1,b1,acc[1][1],0,0,0);
    }
    #pragma unroll
    for (int mi=0; mi<2; mi++)
    #pragma unroll
    for (int ni=0; ni<2; ni++) {
        int r0 = row_a + mi*16 + l4*4;
        int c0 = col_b + ni*16 + l15;
        #pragma unroll
        for (int r=0; r<4; r++)
            C[(size_t)(r0+r)*ldc + c0] = acc[mi][ni][r];
    }
}

// one block per batch row: scores -> softmax -> ctx -> y_tilde -> gates -> state update
__global__ __launch_bounds__(256) void k_step_fused(
    int t,
    const float* __restrict__ dcW, const float* __restrict__ dWhh,
    const __bf16* __restrict__ XWb, const __bf16* __restrict__ Xbf,
    const float* __restrict__ y_prev, const float* __restrict__ W2,
    const float* __restrict__ fcW, const float* __restrict__ fcb,
    const float* __restrict__ W_ih, const float* __restrict__ b_ih, const float* __restrict__ b_hh,
    float* __restrict__ c_f32, float* __restrict__ d_f32,
    __bf16* __restrict__ dc_bf16, float* __restrict__ ctx_last)
{
    int b = blockIdx.x;
    int tid = threadIdx.x, lane = tid & 63, wave = tid >> 6;
    __shared__ float s_scores[64];
    __shared__ float s_red[8];
    __shared__ float s_y;

    // hoist per-lane W2 and dcW slices (same f-slice for every t)
    float w2r[8], dr[8];
    {
        const float4* w2p = (const float4*)(W2 + lane*8);
        const float4* dp  = (const float4*)(dcW + (size_t)b*512 + lane*8);
        float4 w0 = w2p[0], w1 = w2p[1], e0v = dp[0], e1v = dp[1];
        w2r[0]=w0.x; w2r[1]=w0.y; w2r[2]=w0.z; w2r[3]=w0.w;
        w2r[4]=w1.x; w2r[5]=w1.y; w2r[6]=w1.z; w2r[7]=w1.w;
        dr[0]=e0v.x; dr[1]=e0v.y; dr[2]=e0v.z; dr[3]=e0v.w;
        dr[4]=e1v.x; dr[5]=e1v.y; dr[6]=e1v.z; dr[7]=e1v.w;
    }
    // scores: wave w handles t in [w*16, min(w*16+16,63))
    int t0 = wave*16;
    int t1 = t0 + 16 > 63 ? 63 : t0 + 16;
    for (int tt = t0; tt < t1; ++tt) {
        bf16x8 xw = *(const bf16x8*)(XWb + ((size_t)b*TM1 + tt)*512 + lane*8);
        float p = 0.f;
        #pragma unroll
        for (int i=0;i<8;i++) p += w2r[i]*fast_tanh(dr[i] + (float)xw[i]);
        #pragma unroll
        for (int o=32;o;o>>=1) p += __shfl_xor(p, o, 64);
        if (lane==0) s_scores[tt] = p;
    }
    __syncthreads();
    if (wave==0) {
        float s = (lane<63) ? s_scores[lane] : -1e30f;
        float m = s;
        #pragma unroll
        for (int o=32;o;o>>=1) m = fmaxf(m, __shfl_xor(m,o,64));
        float e = (lane<63) ? __expf(s-m) : 0.f;
        float sum = e;
        #pragma unroll
        for (int o=32;o;o>>=1) sum += __shfl_xor(sum,o,64);
        float inv = fast_rcp(sum);
        if (lane<63) s_scores[lane] = e*inv;
    }
    __syncthreads();
    // ctx for 2 e's per thread
    int e0 = tid*2;
    float c0 = 0.f, c1 = 0.f;
    const __bf16* xb = Xbf + (size_t)b*TM1*512 + e0;
    #pragma unroll 9
    for (int tt=0; tt<TM1; ++tt) {
        float bt = s_scores[tt];
        bf16x2 x2 = *(const bf16x2*)(xb + (size_t)tt*512);
        c0 += bt*(float)x2[0];
        c1 += bt*(float)x2[1];
    }
    if (t == 62) {
        ctx_last[(size_t)b*512 + e0]     = c0;
        ctx_last[(size_t)b*512 + e0 + 1] = c1;
    }
    // y_tilde
    float part = fcW[e0]*c0 + fcW[e0+1]*c1;
    #pragma unroll
    for (int o=32;o;o>>=1) part += __shfl_xor(part,o,64);
    if (lane==0) s_red[wave] = part;
    __syncthreads();
    if (tid==0) {
        float y = s_red[0]+s_red[1]+s_red[2]+s_red[3];
        y += fcW[512]*y_prev[(size_t)b*TM1 + t] + fcb[0];
        s_y = y;
    }
    __syncthreads();
    float yv = s_y;
    // gates + state update: 2 c-dims per thread
    #pragma unroll
    for (int r=0;r<2;r++) {
        int k = tid + r*256;
        size_t gb = (size_t)b*2048 + k;
        float gi = dWhh[gb]        + yv*W_ih[k]        + b_ih[k]        + b_hh[k];
        float gf = dWhh[gb+512]    + yv*W_ih[512+k]    + b_ih[512+k]    + b_hh[512+k];
        float gg = dWhh[gb+1024]   + yv*W_ih[1024+k]   + b_ih[1024+k]   + b_hh[1024+k];
        float go = dWhh[gb+1536]   + yv*W_ih[1536+k]   + b_ih[1536+k]   + b_hh[1536+k];
        size_t sk = (size_t)b*512 + k;
        float cn = fast_sigmoid(gf)*c_f32[sk] + fast_sigmoid(gi)*fast_tanh(gg);
        float dn = fast_sigmoid(go)*fast_tanh(cn);
        c_f32[sk] = cn; d_f32[sk] = dn;
        dc_bf16[(size_t)b*1024 + k]       = (__bf16)dn;
        dc_bf16[(size_t)b*1024 + 512 + k] = (__bf16)cn;
    }
}

// final heads: out[0:512]=beta, [512:1024]=sigma, [1024:1536]=gamma
__global__ __launch_bounds__(64) void k_heads(
    const float* __restrict__ d_f32, const float* __restrict__ ctx,
    const float* __restrict__ bW, const float* __restrict__ bb,
    const float* __restrict__ sW, const float* __restrict__ sb,
    const float* __restrict__ gW, const float* __restrict__ gb,
    float* __restrict__ out)
{
    int b = blockIdx.x, lane = threadIdx.x;
    float pb=0.f, ps=0.f, pg=0.f;
    for (int e = lane; e < 1024; e += 64) {
        float v = (e < 512) ? d_f32[(size_t)b*512 + e] : ctx[(size_t)b*512 + e - 512];
        pb += bW[e]*v; ps += sW[e]*v; pg += gW[e]*v;
    }
    #pragma unroll
    for (int o=32;o;o>>=1) {
        pb += __shfl_xor(pb,o,64); ps += __shfl_xor(ps,o,64); pg += __shfl_xor(pg,o,64);
    }
    if (lane==0) {
        out[b]        = pb + bb[0];
        out[512 + b]  = ps + sb[0];
        out[1024 + b] = pg + gb[0];
    }
}

extern "C" void kernel_launch(void* const* d_in, const int* in_sizes, int n_in,
                              void* d_out, int out_size, void* d_ws, size_t ws_size,
                              hipStream_t stream) {
    const float* X      = (const float*)d_in[0];
    const float* y_prev = (const float*)d_in[1];
    const float* W1     = (const float*)d_in[2];
    const float* b1     = (const float*)d_in[3];
    const float* W2     = (const float*)d_in[4];
    // d_in[5] = attn_b2 (softmax-invariant constant shift, skipped)
    const float* fcW    = (const float*)d_in[6];
    const float* fcb    = (const float*)d_in[7];
    const float* W_ih   = (const float*)d_in[8];
    const float* W_hh_f = (const float*)d_in[9];
    const float* b_ih   = (const float*)d_in[10];
    const float* b_hh   = (const float*)d_in[11];
    const float* betaW  = (const float*)d_in[12];
    const float* betab  = (const float*)d_in[13];
    const float* gammaW = (const float*)d_in[14];
    const float* gammab = (const float*)d_in[15];
    const float* sigmaW = (const float*)d_in[16];
    const float* sigmab = (const float*)d_in[17];
    float* out = (float*)d_out;

    size_t off = 0;
    char* ws = (char*)d_ws;
    auto alloc = [&](size_t bytes) { void* p = ws + off; off += (bytes + 255) & ~(size_t)255; return p; };
    __bf16* XWb  = (__bf16*)alloc((size_t)Bn*TM1*512*2);
    __bf16* Xbf  = (__bf16*)alloc((size_t)Bn*TM1*512*2);
    __bf16* Wdc  = (__bf16*)alloc((size_t)512*1024*2);
    __bf16* W1x  = (__bf16*)alloc((size_t)512*512*2);
    __bf16* Whh  = (__bf16*)alloc((size_t)2048*512*2);
    __bf16* dcb  = (__bf16*)alloc((size_t)Bn*1024*2);
    float*  cf   = (float*)alloc((size_t)Bn*512*4);
    float*  df   = (float*)alloc((size_t)Bn*512*4);
    float*  dcW  = (float*)alloc((size_t)Bn*512*4);
    float*  dWhh = (float*)alloc((size_t)Bn*2048*4);
    float*  ctxl = (float*)alloc((size_t)Bn*512*4);

    hipMemsetAsync(dcb, 0, (size_t)Bn*1024*2, stream);
    hipMemsetAsync(cf,  0, (size_t)Bn*512*4, stream);

    k_prep_weights<<<512, 256, 0, stream>>>(W1, W_hh_f, Wdc, W1x, Whh);
    int nx = Bn*TM1*512;
    k_conv_x<<<(nx/4 + 255)/256, 256, 0, stream>>>(X, Xbf, nx);
    k_gemm_xw<<<(Bn*TM1/64)*8, 256, 0, stream>>>(Xbf, W1x, b1, XWb);

    for (int t = 0; t < TM1; ++t) {
        k_step_gemm<<<320, 256, 0, stream>>>(dcb, Wdc, Whh, dcW, dWhh);
        k_step_fused<<<Bn, 256, 0, stream>>>(t, dcW, dWhh, XWb, Xbf, y_prev, W2,
                                             fcW, fcb, W_ih, b_ih, b_hh,
                                             cf, df, dcb, ctxl);
    }
    k_heads<<<Bn, 64, 0, stream>>>(df, ctxl, betaW, betab, sigmaW, sigmab, gammaW, gammab, out);
}